// Round 8
// baseline (230.281 us; speedup 1.0000x reference)
//
#include <hip/hip_runtime.h>
#include <hip/hip_fp16.h>

// Problem constants
#define B_     8
#define NCAM   5
#define J_     15
#define H_     128
#define W_     240
#define NB     128000             // bins = 80*80*20
#define HW_    (H_ * W_)          // 30720
// R8: BATCH-PAIR layout. sample_grid (and thus addr+weights) is identical
// across batches, and all batches read the SAME 4 pixels per bin. Pack two
// batches' images interleaved: dword[y][x] = (f16 hm_b0(y,x), f16 hm_b1(y,x))
// (30720 dw = 122.9 KB, single LDS buffer). Per bin: 2x ds_read2_b32
// (offsets 0,1 and 240,241) serve BOTH batches -> LDS instrs/sample halved
// vs R7 (no divergent odd branch), weight traffic halved (one load feeds
// two accs), addr VALU halved. Cost: serial staging (two f32 images).
#define TPB    1024
#define NBP    (B_ / 2)           // 4 batch-pairs
#define NBPJ   (NBP * J_)         // 60
#define NCHUNK 16                 // 960 blocks
#define BPB    (NB / NCHUNK)      // 8000 bins per block
#define ITEMS  8                  // 8000/1024 = 7.8125; item 7 partial (tid<832)
#define NBLK   (NBPJ * NCHUNK)    // 960

typedef __fp16 fp16x2 __attribute__((ext_vector_type(2)));

__device__ __forceinline__ unsigned int pkrtz(float lo, float hi) {
    fp16x2 h = __builtin_amdgcn_cvt_pkrtz(lo, hi);  // v_cvt_pkrtz_f16_f32
    return __builtin_bit_cast(unsigned int, h);
}

// f32 dot of two f16 pairs: v_dot2_f32_f16 (f32 accumulate).
__device__ __forceinline__ float fdot2(unsigned int d, unsigned int w, float c) {
#if __has_builtin(__builtin_amdgcn_fdot2)
    return __builtin_amdgcn_fdot2(__builtin_bit_cast(fp16x2, d),
                                  __builtin_bit_cast(fp16x2, w), c, false);
#else
    __half2 p = __hmul2(__builtin_bit_cast(__half2, d),
                        __builtin_bit_cast(__half2, w));
    return c + __low2float(p) + __high2float(p);
#endif
}

// Bilinear weights, padding_mode='zeros' validity folded into clamped 2x2
// window (math identical to validated R0-R7; row-pair packing as R7).
// Camera-mean 1/5 folded in.
// addr16 = yc*240 + xc (max 30478, fits u16)
// w0pk = (0.2*a0*b0, 0.2*a1*b0)  -- row yc,   cols (xc, xc+1)
// w1pk = (0.2*a0*b1, 0.2*a1*b1)  -- row yc+1, cols (xc, xc+1)
__device__ __forceinline__ void bilinear_rec(float gx, float gy,
                                             unsigned int& addr,
                                             unsigned int& w0pk,
                                             unsigned int& w1pk) {
    const float ix = (gx + 1.0f) * (0.5f * (W_ - 1));
    const float iy = (gy + 1.0f) * (0.5f * (H_ - 1));
    const float x0f = floorf(ix);
    const float y0f = floorf(iy);
    const float wx1 = ix - x0f, wx0 = 1.0f - wx1;
    const float wy1 = iy - y0f, wy0 = 1.0f - wy1;
    const int x0 = (int)x0f;
    const int y0 = (int)y0f;
    const int xc = min(max(x0, 0), W_ - 2);
    const int yc = min(max(y0, 0), H_ - 2);
    const float vx0 = (x0 >= 0  && x0 <= W_ - 1) ? wx0 : 0.0f;
    const float vx1 = (x0 >= -1 && x0 <= W_ - 2) ? wx1 : 0.0f;
    const float vy0 = (y0 >= 0  && y0 <= H_ - 1) ? wy0 : 0.0f;
    const float vy1 = (y0 >= -1 && y0 <= H_ - 2) ? wy1 : 0.0f;
    const bool xhi = (x0 == W_ - 1);
    const bool xlo = (x0 == -1);
    const bool yhi = (y0 == H_ - 1);
    const bool ylo = (y0 == -1);
    const float a0 = (xhi ? 0.0f : vx0) + (xlo ? vx1 : 0.0f);
    const float a1 = (xhi ? vx0 : 0.0f) + (xlo ? 0.0f : vx1);
    const float b0 = (yhi ? 0.0f : vy0) + (ylo ? vy1 : 0.0f);
    const float b1 = (yhi ? vy0 : 0.0f) + (ylo ? 0.0f : vy1);
    addr = (unsigned int)(yc * W_ + xc);
    w0pk = pkrtz(0.2f * (a0 * b0), 0.2f * (a1 * b0));
    w1pk = pkrtz(0.2f * (a0 * b1), 0.2f * (a1 * b1));
}

__global__ __launch_bounds__(256) void weights_kernel(
    const float* __restrict__ sgrid,          // [NCAM, NB, 2]
    unsigned short* __restrict__ addr16,      // [NCAM*NB]
    uint2* __restrict__ wpk)                  // [NCAM*NB]
{
    const int i = blockIdx.x * 256 + threadIdx.x;
    if (i >= NCAM * NB) return;
    const float2 g = ((const float2*)sgrid)[i];
    unsigned int a, w0, w1;
    bilinear_rec(g.x, g.y, a, w0, w1);
    addr16[i] = (unsigned short)a;
    wpk[i] = make_uint2(w0, w1);
}

// ---- named-scalar macros (no arrays; all indices literal) ----
#define LOADI(IT) \
    const unsigned int a##IT = ap[(IT) * TPB + tid]; \
    const uint2        w##IT = wp[(IT) * TPB + tid];
// tail item: clamped in-bounds load + zero weights (garbage*0 == 0)
#define LOADI_T(IT) \
    const int rt##IT = min((IT) * TPB + tid, BPB - 1); \
    const unsigned int a##IT = ap[rt##IT]; \
    const uint2        wt##IT = wp[rt##IT]; \
    const uint2        w##IT = tail_ok ? wt##IT : make_uint2(0u, 0u);
// 4 corner dwords, each holding (b0,b1) f16 pair: two ds_read2_b32
// (offset pairs (0,1) and (240,241), both <= 255 dword-offset limit).
#define DSI(IT) \
    const unsigned int d00_##IT = s_img[a##IT]; \
    const unsigned int d01_##IT = s_img[a##IT + 1u]; \
    const unsigned int d10_##IT = s_img[a##IT + 240u]; \
    const unsigned int d11_##IT = s_img[a##IT + 241u];
// perm splits batches: lo-halves -> b0's (v@xc, v@xc+1), hi-halves -> b1's.
// perm(X, Y, 0x05040100) = (lo16 Y, lo16 X); 0x07060302 = (hi16 Y, hi16 X).
#define DOTI(IT) { \
    const unsigned int r00_##IT = __builtin_amdgcn_perm(d01_##IT, d00_##IT, 0x05040100u); \
    const unsigned int r01_##IT = __builtin_amdgcn_perm(d01_##IT, d00_##IT, 0x07060302u); \
    const unsigned int r10_##IT = __builtin_amdgcn_perm(d11_##IT, d10_##IT, 0x05040100u); \
    const unsigned int r11_##IT = __builtin_amdgcn_perm(d11_##IT, d10_##IT, 0x07060302u); \
    accA##IT = fdot2(r10_##IT, w##IT.y, fdot2(r00_##IT, w##IT.x, accA##IT)); \
    accB##IT = fdot2(r11_##IT, w##IT.y, fdot2(r01_##IT, w##IT.x, accB##IT)); }
#define OUTI(IT) \
    if ((IT) * TPB + tid < BPB) { \
        oA[(IT) * TPB + tid] = fminf(fmaxf(accA##IT, 0.0f), 1.0f); \
        oB[(IT) * TPB + tid] = fminf(fmaxf(accB##IT, 0.0f), 1.0f); }

// Static LDS 122.9 KB -> 1 block/CU, 16 waves. Opaque-bpb fence levels
// (R6/R7-proven) keep peak live ~55 regs < the hard 64-VGPR budget.
__global__ __launch_bounds__(TPB, 4) void project_kernel(
    const float* __restrict__ hm,             // [B, NCAM, J, H, W]
    const unsigned short* __restrict__ addr16,
    const uint2* __restrict__ wpk,
    float* __restrict__ out,                  // [B, J, NB]
    int bpb)                                  // == BPB; runtime-opaque fence
{
    __shared__ unsigned int s_img[HW_];       // STATIC: 122880 B
    const int tid   = threadIdx.x;
    // bpj-major: same-image blocks at bids bpj+60k -> 2 XCDs per image set.
    const int bpj   = blockIdx.x % NBPJ;
    const int chunk = blockIdx.x / NBPJ;
    const int bp    = bpj / J_;
    const int j     = bpj % J_;
    const int b0    = 2 * bp;
    const int b1    = 2 * bp + 1;
    const int bin0  = chunk * BPB;
    // item 7: r = 7*1024+tid < 8000  <=>  tid < 832 (wave-uniform)
    const bool tail_ok = (tid < BPB - (ITEMS - 1) * TPB);

    float accA0 = 0.f, accA1 = 0.f, accA2 = 0.f, accA3 = 0.f;
    float accA4 = 0.f, accA5 = 0.f, accA6 = 0.f, accA7 = 0.f;
    float accB0 = 0.f, accB1 = 0.f, accB2 = 0.f, accB3 = 0.f;
    float accB4 = 0.f, accB5 = 0.f, accB6 = 0.f, accB7 = 0.f;

    for (int n = 0; n < NCAM; ++n) {
        const unsigned short* __restrict__ ap = addr16 + n * NB + bin0;
        const uint2* __restrict__ wp = wpk + n * NB + bin0;
        // Level-0 weight loads issue before staging: L2/L3 latency (~400cy)
        // hides under the ~5k-cycle staging phase.
        LOADI(0) LOADI(1)
        __syncthreads();          // prev camera's sampling done
        {   // Stage both images interleaved: linear, no row arithmetic.
            const float4* __restrict__ sA =
                (const float4*)(hm + (((size_t)b0 * NCAM + n) * J_ + j) * HW_);
            const float4* __restrict__ sB =
                (const float4*)(hm + (((size_t)b1 * NCAM + n) * J_ + j) * HW_);
            uint4* __restrict__ dst4 = (uint4*)s_img;
            for (int gi = tid; gi < HW_ / 4; gi += TPB) {
                const float4 ta = sA[gi];
                const float4 tb = sB[gi];
                dst4[gi] = make_uint4(pkrtz(ta.x, tb.x), pkrtz(ta.y, tb.y),
                                      pkrtz(ta.z, tb.z), pkrtz(ta.w, tb.w));
            }
        }
        __syncthreads();
        // Fence levels (all guards true at runtime; bpb opaque): 4 levels x
        // 2 pair-items. Level g: issue level g+1 loads | ds(g) | dot(g).
        if (tid < bpb) {                                       // L0
            LOADI(2) LOADI(3)
            DSI(0) DSI(1) DOTI(0) DOTI(1)
            if (1 * TPB + tid < bpb) {                         // L1
                LOADI(4) LOADI(5)
                DSI(2) DSI(3) DOTI(2) DOTI(3)
                if (2 * TPB + tid < bpb) {                     // L2
                    LOADI(6) LOADI_T(7)
                    DSI(4) DSI(5) DOTI(4) DOTI(5)
                    if (3 * TPB + tid < bpb) {                 // L3
                        DSI(6) DSI(7) DOTI(6) DOTI(7)
                    }
                }
            }
        }
    }

    float* __restrict__ oA = out + ((size_t)(b0 * J_ + j)) * NB + bin0;
    float* __restrict__ oB = out + ((size_t)(b1 * J_ + j)) * NB + bin0;
    OUTI(0) OUTI(1) OUTI(2) OUTI(3) OUTI(4) OUTI(5) OUTI(6) OUTI(7)
}

// Fallback (tiny ws): R1-style f32-LDS kernel, inline weights. 600 blocks.
#define NBJ    (B_ * J_)             // 120
#define FB_SMEM   (HW_ * 4)
#define FB_NCHUNK 5
#define FB_BPB    (NB / FB_NCHUNK)   // 25600
#define FB_ITEMS  (FB_BPB / TPB)     // 25
__global__ __launch_bounds__(TPB) void project_fallback(
    const float* __restrict__ hm,
    const float* __restrict__ sgrid,
    float* __restrict__ out)
{
    extern __shared__ float s_f32[];
    const int tid   = threadIdx.x;
    const int bj    = blockIdx.x % NBJ;
    const int chunk = blockIdx.x / NBJ;
    const int b     = bj / J_;
    const int j     = bj % J_;
    const int bin0  = chunk * FB_BPB;

    float acc[FB_ITEMS];
#pragma unroll
    for (int it = 0; it < FB_ITEMS; ++it) acc[it] = 0.0f;

    for (int n = 0; n < NCAM; ++n) {
        __syncthreads();
        const float4* __restrict__ src =
            (const float4*)(hm + (((size_t)b * NCAM + n) * J_ + j) * HW_);
        float4* dst = (float4*)s_f32;
        for (int i = tid; i < HW_ / 4; i += TPB) dst[i] = src[i];
        __syncthreads();
        const float2* __restrict__ g2 = (const float2*)sgrid + n * NB + bin0;
#pragma unroll
        for (int it = 0; it < FB_ITEMS; ++it) {
            const float2 g = g2[it * TPB + tid];
            const float ix = (g.x + 1.0f) * (0.5f * (W_ - 1));
            const float iy = (g.y + 1.0f) * (0.5f * (H_ - 1));
            const float x0f = floorf(ix), y0f = floorf(iy);
            const float wx1 = ix - x0f, wx0 = 1.0f - wx1;
            const float wy1 = iy - y0f, wy0 = 1.0f - wy1;
            const int x0 = (int)x0f, y0 = (int)y0f;
            const int xc = min(max(x0, 0), W_ - 2);
            const int yc = min(max(y0, 0), H_ - 2);
            const float vx0 = (x0 >= 0  && x0 <= W_ - 1) ? wx0 : 0.0f;
            const float vx1 = (x0 >= -1 && x0 <= W_ - 2) ? wx1 : 0.0f;
            const float vy0 = (y0 >= 0  && y0 <= H_ - 1) ? wy0 : 0.0f;
            const float vy1 = (y0 >= -1 && y0 <= H_ - 2) ? wy1 : 0.0f;
            const bool xhi = (x0 == W_ - 1), xlo = (x0 == -1);
            const bool yhi = (y0 == H_ - 1), ylo = (y0 == -1);
            const float a0 = (xhi ? 0.0f : vx0) + (xlo ? vx1 : 0.0f);
            const float a1 = (xhi ? vx0 : 0.0f) + (xlo ? 0.0f : vx1);
            const float b0 = (yhi ? 0.0f : vy0) + (ylo ? vy1 : 0.0f);
            const float b1 = (yhi ? vy0 : 0.0f) + (ylo ? 0.0f : vy1);
            const float* r0 = s_f32 + (yc * W_ + xc);
            acc[it] += b0 * (a0 * r0[0] + a1 * r0[1])
                     + b1 * (a0 * r0[W_] + a1 * r0[W_ + 1]);
        }
    }
    float* __restrict__ o = out + (size_t)bj * NB + bin0;
#pragma unroll
    for (int it = 0; it < FB_ITEMS; ++it)
        o[it * TPB + tid] = fminf(fmaxf(acc[it] * 0.2f, 0.0f), 1.0f);
}

extern "C" void kernel_launch(void* const* d_in, const int* in_sizes, int n_in,
                              void* d_out, int out_size, void* d_ws, size_t ws_size,
                              hipStream_t stream) {
    const float* hm = (const float*)d_in[0];   // [8,5,15,128,240] f32
    const float* sg = (const float*)d_in[1];   // [5,128000,2] f32
    float* out = (float*)d_out;                // [8,15,128000] f32

    (void)hipFuncSetAttribute((const void*)project_fallback,
                              hipFuncAttributeMaxDynamicSharedMemorySize, FB_SMEM);

    const size_t addr_bytes = (size_t)NCAM * NB * sizeof(unsigned short); // 1.28 MB
    const size_t wpk_bytes  = (size_t)NCAM * NB * sizeof(uint2);          // 5.12 MB
    if (ws_size >= addr_bytes + wpk_bytes) {
        unsigned short* addr16 = (unsigned short*)d_ws;
        uint2* wpk = (uint2*)((char*)d_ws + addr_bytes);
        weights_kernel<<<(NCAM * NB + 255) / 256, 256, 0, stream>>>(sg, addr16, wpk);
        project_kernel<<<NBLK, TPB, 0, stream>>>(hm, addr16, wpk, out, BPB);
    } else {
        project_fallback<<<NBJ * FB_NCHUNK, TPB, FB_SMEM, stream>>>(hm, sg, out);
    }
}